// Round 1
// 528.045 us; speedup vs baseline: 1.1590x; 1.1590x over previous
//
#include <hip/hip_runtime.h>
#include <hip/hip_bf16.h>

typedef __hip_bfloat16 bf16;
typedef __attribute__((ext_vector_type(8))) short short8;
typedef __attribute__((ext_vector_type(4))) float floatx4;
typedef __attribute__((ext_vector_type(4))) unsigned short ushortx4;

#define N_NODESC 50000
#define MPAD     50016     // padded to 32-row tiles
#define N_EDGESC 800000
#define E_TOTC   850000    // + self loops
#define IN_DIMC  128
#define FDIM     256       // HEADS*HID
#define HEADSC   4
#define HIDC     64
#define NEG_SLOPE 0.2f
#define CHUNK    32

__device__ __forceinline__ float bits2f(unsigned short b){
  return __uint_as_float(((unsigned)b) << 16);
}

__device__ __forceinline__ float wave_sum(float v){
  #pragma unroll
  for (int m = 32; m > 0; m >>= 1) v += __shfl_xor(v, m, 64);
  return v;
}
__device__ __forceinline__ float wave_max(float v){
  #pragma unroll
  for (int m = 32; m > 0; m >>= 1) v = fmaxf(v, __shfl_xor(v, m, 64));
  return v;
}
// reductions within 32-lane half-waves (lane groups stay inside xor<32)
__device__ __forceinline__ float g32_sum(float v){
  #pragma unroll
  for (int m = 16; m > 0; m >>= 1) v += __shfl_xor(v, m, 64);
  return v;
}
__device__ __forceinline__ float g32_max(float v){
  #pragma unroll
  for (int m = 16; m > 0; m >>= 1) v = fmaxf(v, __shfl_xor(v, m, 64));
  return v;
}

// ---------- edge_attr column means (for self-loop fill) ----------
__global__ __launch_bounds__(256) void k_mean(const float* __restrict__ ea,
                                              float* __restrict__ meanacc){
  float s0 = 0.f, s1 = 0.f, s2 = 0.f;
  for (int i = blockIdx.x * blockDim.x + threadIdx.x; i < N_EDGESC;
       i += gridDim.x * blockDim.x){
    s0 += ea[i*3+0]; s1 += ea[i*3+1]; s2 += ea[i*3+2];
  }
  s0 = wave_sum(s0); s1 = wave_sum(s1); s2 = wave_sum(s2);
  __shared__ float red[3][4];
  int lane = threadIdx.x & 63, w = threadIdx.x >> 6;
  if (lane == 0){ red[0][w] = s0; red[1][w] = s1; red[2][w] = s2; }
  __syncthreads();
  if (threadIdx.x == 0){
    float t0 = 0.f, t1 = 0.f, t2 = 0.f;
    for (int i = 0; i < 4; i++){ t0 += red[0][i]; t1 += red[1][i]; t2 += red[2][i]; }
    atomicAdd(&meanacc[0], t0); atomicAdd(&meanacc[1], t1); atomicAdd(&meanacc[2], t2);
  }
}

// ---------- convert x (fp32) -> xb (bf16 bits), zero pad rows ----------
__global__ __launch_bounds__(256) void k_cvtx(const float* __restrict__ x,
                                              unsigned short* __restrict__ xb){
  size_t tid = (size_t)blockIdx.x * 256 + threadIdx.x;
  size_t base = tid * 4;
  const size_t NELEM = (size_t)N_NODESC * IN_DIMC;   // 6,400,000
  ushortx4 o;
  if (base + 3 < NELEM){
    const float4* xp = (const float4*)(x + base);
    float4 v = *xp;
    o[0] = (unsigned short)(__float_as_uint(v.x) >> 16);
    o[1] = (unsigned short)(__float_as_uint(v.y) >> 16);
    o[2] = (unsigned short)(__float_as_uint(v.z) >> 16);
    o[3] = (unsigned short)(__float_as_uint(v.w) >> 16);
  } else {
    #pragma unroll
    for (int f = 0; f < 4; f++){
      size_t i = base + f;
      float v = (i < NELEM) ? x[i] : 0.f;
      o[f] = (unsigned short)(__float_as_uint(v) >> 16);
    }
  }
  *(ushortx4*)(xb + base) = o;
}

// ---------- convert W1l,W1r -> MFMA-frag-contiguous bf16 layout ----------
// out[mat][kblk(16)][n(256)][j(8)] = W[kblk*8+j][n]
__global__ __launch_bounds__(256) void k_cvtw(const float* __restrict__ W1l,
                                              const float* __restrict__ W1r,
                                              unsigned short* __restrict__ Bfrag){
  int idx = blockIdx.x * 256 + threadIdx.x;   // < 65536
  int mat = idx >> 15;
  int r   = idx & 32767;       // k*256+n
  int k   = r >> 8, n = r & 255;
  float v = mat ? W1r[r] : W1l[r];
  int pos = (mat << 15) + (((k >> 3) << 8) + n) * 8 + (k & 7);
  Bfrag[pos] = (unsigned short)(__float_as_uint(v) >> 16);
}

// ---------- MFMA dual GEMM: xl = x@W1l, xr = x@W1r (bf16 out) ----------
__global__ __launch_bounds__(256) void k_gemm_mfma(const unsigned short* __restrict__ xb,
                                                   const unsigned short* __restrict__ Bfrag,
                                                   unsigned short* __restrict__ xl,
                                                   unsigned short* __restrict__ xr){
  const int mat = blockIdx.y;
  const int r0  = blockIdx.x * 32;
  const int w = threadIdx.x >> 6, lane = threadIdx.x & 63;
  const int quad = lane >> 4, l16 = lane & 15;
  const unsigned short* Bm = Bfrag + ((size_t)mat << 15);
  unsigned short* C = mat ? xr : xl;

  short8 afr[2][4];
  #pragma unroll
  for (int ms = 0; ms < 2; ms++)
    #pragma unroll
    for (int ks = 0; ks < 4; ks++){
      const unsigned short* p = xb + (size_t)(r0 + ms*16 + l16) * IN_DIMC + ks*32 + quad*8;
      afr[ms][ks] = *reinterpret_cast<const short8*>(p);
    }
  const int n0 = w * 64;
  floatx4 acc[2][4];
  #pragma unroll
  for (int ms = 0; ms < 2; ms++)
    #pragma unroll
    for (int ns = 0; ns < 4; ns++){
      floatx4 z = {0.f, 0.f, 0.f, 0.f};
      acc[ms][ns] = z;
    }
  #pragma unroll
  for (int ks = 0; ks < 4; ks++){
    #pragma unroll
    for (int ns = 0; ns < 4; ns++){
      int n = n0 + ns*16 + l16;
      int kblk = ks*4 + quad;
      short8 bfr = *reinterpret_cast<const short8*>(Bm + ((size_t)kblk*256 + n)*8);
      acc[0][ns] = __builtin_amdgcn_mfma_f32_16x16x32_bf16(afr[0][ks], bfr, acc[0][ns], 0, 0, 0);
      acc[1][ns] = __builtin_amdgcn_mfma_f32_16x16x32_bf16(afr[1][ks], bfr, acc[1][ns], 0, 0, 0);
    }
  }
  #pragma unroll
  for (int ms = 0; ms < 2; ms++)
    #pragma unroll
    for (int ns = 0; ns < 4; ns++){
      int col = n0 + ns*16 + l16;
      #pragma unroll
      for (int rg = 0; rg < 4; rg++){
        int row = r0 + ms*16 + quad*4 + rg;
        C[(size_t)row * FDIM + col] = (unsigned short)(__float_as_uint(acc[ms][ns][rg]) >> 16);
      }
    }
}

// ---------- CSR build: count, scan, scatter(+edge-attr pre-gather) ----------
__global__ __launch_bounds__(256) void k_count(const int* __restrict__ ei,
                                               int* __restrict__ deg){
  int e = blockIdx.x * blockDim.x + threadIdx.x;
  if (e >= E_TOTC) return;
  int dst = (e < N_EDGESC) ? ei[N_EDGESC + e] : (e - N_EDGESC);
  atomicAdd(&deg[dst], 1);
}

__global__ __launch_bounds__(1024) void k_scan(const int* __restrict__ deg,
                                               int* __restrict__ offsets,
                                               int* __restrict__ cursor){
  const int n = N_NODESC;
  const int T = 1024;
  const int CH = (n + T - 1) / T;
  int t = threadIdx.x;
  int beg = t * CH, end = min(beg + CH, n);
  int s = 0;
  for (int i = beg; i < end; i++) s += deg[i];
  __shared__ int sums[1024];
  sums[t] = s;
  __syncthreads();
  for (int off = 1; off < T; off <<= 1){
    int v = (t >= off) ? sums[t - off] : 0;
    __syncthreads();
    sums[t] += v;
    __syncthreads();
  }
  int run = sums[t] - s;
  for (int i = beg; i < end; i++){
    offsets[i] = run; cursor[i] = run; run += deg[i];
  }
  if (t == T - 1) offsets[n] = sums[T - 1];
}

// packed edge record: .x = src (int bits), .y/.z/.w = edge_attr
__global__ __launch_bounds__(256) void k_scatter(const int* __restrict__ ei,
                                                 const float* __restrict__ ea,
                                                 const float* __restrict__ meanacc,
                                                 const float* __restrict__ W2e,
                                                 int* __restrict__ cursor,
                                                 int* __restrict__ srcp,
                                                 float4* __restrict__ rec,
                                                 float* __restrict__ ef2){
  int e = blockIdx.x * blockDim.x + threadIdx.x;
  if (e >= E_TOTC) return;
  int src, dst; float e0, e1, e2;
  if (e < N_EDGESC){
    src = ei[e]; dst = ei[N_EDGESC + e];
    e0 = ea[e*3+0]; e1 = ea[e*3+1]; e2 = ea[e*3+2];
  } else {
    src = dst = e - N_EDGESC;
    const float inv = 1.0f / (float)N_EDGESC;
    e0 = meanacc[0]*inv; e1 = meanacc[1]*inv; e2 = meanacc[2]*inv;
  }
  int pos = atomicAdd(&cursor[dst], 1);
  srcp[pos] = src;
  float4 r; r.x = __int_as_float(src); r.y = e0; r.z = e1; r.w = e2;
  rec[pos] = r;
  ef2[pos] = e0*W2e[0] + e1*W2e[1] + e2*W2e[2];
}

// ---------- layer-1 FUSED, chunked two-phase ----------
// phase A : waves own edges (gather + 16-lane logit reduce), all weights in regs
// phase A5: lane-parallel chunk max / exp / sum per head (no redundant exp)
// phase B : 2 features/thread (b32 LDS reads), edges parity-split across waves
__global__ __launch_bounds__(256) void k_attn1(const int* __restrict__ offsets,
                                               const float4* __restrict__ rec,
                                               const unsigned short* __restrict__ xl,
                                               const unsigned short* __restrict__ xr,
                                               const float* __restrict__ W1e,
                                               const float* __restrict__ att1,
                                               const float* __restrict__ b1,
                                               const float* __restrict__ W2l,
                                               const float* __restrict__ W2r,
                                               float* __restrict__ sl,
                                               float* __restrict__ sr){
  const int n = blockIdx.x;
  const int t = threadIdx.x, lane = t & 63, w = t >> 6;
  __shared__ unsigned short xls[CHUNK][FDIM];   // 16 KB
  __shared__ float lgs[HEADSC][CHUNK];          // 512 B
  __shared__ float comb[128][2];                // 1 KB
  __shared__ float sred[2][2];

  // ---- phase-A invariants in registers (feature f0..f0+3 per lane) ----
  const int f0 = lane * 4;
  float xrv[4], w0[4], w1[4], w2[4], av[4];
  {
    ushortx4 xw = *(const ushortx4*)(xr + (size_t)n * FDIM + f0);
    float4 a = *(const float4*)(W1e + f0);
    float4 b = *(const float4*)(W1e + FDIM + f0);
    float4 c = *(const float4*)(W1e + 2*FDIM + f0);
    float4 d = *(const float4*)(att1 + f0);
    xrv[0]=bits2f(xw[0]); xrv[1]=bits2f(xw[1]); xrv[2]=bits2f(xw[2]); xrv[3]=bits2f(xw[3]);
    w0[0]=a.x; w0[1]=a.y; w0[2]=a.z; w0[3]=a.w;
    w1[0]=b.x; w1[1]=b.y; w1[2]=b.z; w1[3]=b.w;
    w2[0]=c.x; w2[1]=c.y; w2[2]=c.z; w2[3]=c.w;
    av[0]=d.x; av[1]=d.y; av[2]=d.z; av[3]=d.w;
  }
  const int beg = offsets[n], end = offsets[n + 1];
  // ---- phase-B role: features (t&127)*2, (t&127)*2+1 ; edge parity t>>7 ----
  const int fp2 = (t & 127) * 2;
  const int par = t >> 7;
  const int li  = lane & 31;
  const int hh  = ((w & 1) << 1) | (lane >> 5);  // head tracked by this thread
  float m = -1e30f, den = 0.f, acc0 = 0.f, acc1 = 0.f;

  for (int c0 = beg; c0 < end; c0 += CHUNK){
    int cnt = min(CHUNK, end - c0);
    // ---- phase A (1-deep software pipeline on the edge record) ----
    {
      int i = w;
      float4 rc;
      if (i < cnt) rc = rec[c0 + i];
      while (i < cnt){
        int src = __builtin_amdgcn_readfirstlane(__float_as_int(rc.x));
        const ushortx4 raw = *(const ushortx4*)(xl + (size_t)src * FDIM + f0);
        float e0 = rc.y, e1 = rc.z, e2 = rc.w;
        int in_ = i + 4;
        if (in_ < cnt) rc = rec[c0 + in_];        // next record in flight
        float pp = 0.f;
        #pragma unroll
        for (int f = 0; f < 4; f++){
          float v = bits2f(raw[f]) + xrv[f] + e0*w0[f] + e1*w1[f] + e2*w2[f];
          v = fmaxf(v, NEG_SLOPE * v);
          pp += v * av[f];
        }
        pp += __shfl_xor(pp, 1, 64);
        pp += __shfl_xor(pp, 2, 64);
        pp += __shfl_xor(pp, 4, 64);
        pp += __shfl_xor(pp, 8, 64);
        if ((lane & 15) == 0) lgs[lane >> 4][i] = pp;
        *(ushortx4*)&xls[i][f0] = raw;
        i = in_;
      }
    }
    __syncthreads();
    // ---- phase A5: lane-parallel online-softmax update (per 32-lane head group) ----
    float lg = (li < cnt) ? lgs[hh][li] : -1e30f;
    float cm = g32_max(lg);
    float mn = fmaxf(m, cm);
    float al = (li < cnt) ? __expf(lg - mn) : 0.f;
    float cs = g32_sum(al);
    float corr = __expf(m - mn);
    den = den * corr + cs;
    m = mn;
    acc0 *= corr; acc1 *= corr;
    // ---- phase B: accumulate; lane holds al for edge li of its head ----
    const int albase = lane & 32;
    for (int i = par; i < cnt; i += 2){
      float ali = __shfl(al, albase + i, 64);
      unsigned rv = *(const unsigned*)&xls[i][fp2];
      acc0 += ali * __uint_as_float(rv << 16);
      acc1 += ali * __uint_as_float(rv & 0xffff0000u);
    }
    __syncthreads();
  }
  // ---- combine edge-parity halves, epilogue ----
  if (t >= 128){ comb[t - 128][0] = acc0; comb[t - 128][1] = acc1; }
  __syncthreads();
  if (t < 128){
    float invd = 1.0f / den;
    float2 bb = *(const float2*)(b1 + 2*t);
    float h0v = (acc0 + comb[t][0]) * invd + bb.x;
    float h1v = (acc1 + comb[t][1]) * invd + bb.y;
    h0v = (h0v > 0.f) ? h0v : (__expf(h0v) - 1.f);   // ELU
    h1v = (h1v > 0.f) ? h1v : (__expf(h1v) - 1.f);
    float2 wl = *(const float2*)(W2l + 2*t);
    float2 wr = *(const float2*)(W2r + 2*t);
    float pa = h0v*wl.x + h1v*wl.y;
    float pb = h0v*wr.x + h1v*wr.y;
    pa = wave_sum(pa); pb = wave_sum(pb);
    if (lane == 0){ sred[0][w] = pa; sred[1][w] = pb; }
  }
  __syncthreads();
  if (t == 0){
    sl[n] = sred[0][0] + sred[0][1];
    sr[n] = sred[1][0] + sred[1][1];
  }
}

// ---------- layer-2 FUSED: edge logits + online softmax -> scores ----------
__global__ __launch_bounds__(256) void k_attn2(const int* __restrict__ offsets,
                                               const int* __restrict__ srcp,
                                               const float* __restrict__ ef2,
                                               const float* __restrict__ att2,
                                               const float* __restrict__ b2p,
                                               const float* __restrict__ sl,
                                               const float* __restrict__ sr,
                                               float* __restrict__ scores,
                                               float* __restrict__ out){
  int t = threadIdx.x, lane = t & 63;
  int n = blockIdx.x * 4 + (t >> 6);
  if (n >= N_NODESC) return;
  const float attv = att2[0];
  const float srn = sr[n];
  int beg = offsets[n], end = offsets[n + 1];
  float m = -1e30f, den = 0.f, num = 0.f;
  for (int j = beg + lane; j < end; j += 64){
    float slv = sl[srcp[j]];
    float v = slv + srn + ef2[j];
    v = (v > 0.f) ? v : NEG_SLOPE * v;
    float lg = v * attv;
    float mn = fmaxf(m, lg);
    float corr = __expf(m - mn);
    float pe   = __expf(lg - mn);
    den = den * corr + pe;
    num = num * corr + pe * slv;
    m = mn;
  }
  float mg = wave_max(m);
  float scale = __expf(m - mg);
  float deng = wave_sum(den * scale);
  float numg = wave_sum(num * scale);
  if (lane == 0){
    float s = numg / deng + b2p[0];
    scores[n] = s;
    out[N_NODESC + n] = s;
  }
}

// ---------- global softmax over scores ----------
__device__ __forceinline__ unsigned fkey(float f){
  unsigned u = __float_as_uint(f);
  return u ^ ((u >> 31) ? 0xFFFFFFFFu : 0x80000000u);
}
__device__ __forceinline__ float funkey(unsigned k){
  unsigned u = (k >> 31) ? (k ^ 0x80000000u) : ~k;
  return __uint_as_float(u);
}

__global__ __launch_bounds__(256) void k_smax_max(const float* __restrict__ scores,
                                                  unsigned* __restrict__ redmax){
  float m = -1e30f;
  for (int i = blockIdx.x * blockDim.x + threadIdx.x; i < N_NODESC;
       i += gridDim.x * blockDim.x)
    m = fmaxf(m, scores[i]);
  m = wave_max(m);
  __shared__ float ws_[4];
  int lane = threadIdx.x & 63, w = threadIdx.x >> 6;
  if (lane == 0) ws_[w] = m;
  __syncthreads();
  if (threadIdx.x == 0){
    for (int i = 1; i < 4; i++) m = fmaxf(m, ws_[i]);
    atomicMax(redmax, fkey(m));
  }
}

__global__ __launch_bounds__(256) void k_smax_sum(const float* __restrict__ scores,
                                                  const unsigned* __restrict__ redmax,
                                                  float* __restrict__ redsum){
  float mx = funkey(*redmax);
  float s = 0.f;
  for (int i = blockIdx.x * blockDim.x + threadIdx.x; i < N_NODESC;
       i += gridDim.x * blockDim.x)
    s += __expf(scores[i] - mx);
  s = wave_sum(s);
  __shared__ float ws_[4];
  int lane = threadIdx.x & 63, w = threadIdx.x >> 6;
  if (lane == 0) ws_[w] = s;
  __syncthreads();
  if (threadIdx.x == 0){
    float t = 0.f;
    for (int i = 0; i < 4; i++) t += ws_[i];
    atomicAdd(redsum, t);
  }
}

__global__ __launch_bounds__(256) void k_smax_write(const float* __restrict__ scores,
                                                    const unsigned* __restrict__ redmax,
                                                    const float* __restrict__ redsum,
                                                    float* __restrict__ out){
  int i = blockIdx.x * blockDim.x + threadIdx.x;
  if (i >= N_NODESC) return;
  float mx = funkey(*redmax);
  float inv = 1.0f / (*redsum);
  out[i] = __expf(scores[i] - mx) * inv;
}

extern "C" void kernel_launch(void* const* d_in, const int* in_sizes, int n_in,
                              void* d_out, int out_size, void* d_ws, size_t ws_size,
                              hipStream_t stream) {
  const float* x    = (const float*)d_in[0];
  const float* ea   = (const float*)d_in[1];
  const float* W1l  = (const float*)d_in[2];
  const float* W1r  = (const float*)d_in[3];
  const float* W1e  = (const float*)d_in[4];
  const float* att1 = (const float*)d_in[5];
  const float* b1   = (const float*)d_in[6];
  const float* W2l  = (const float*)d_in[7];
  const float* W2r  = (const float*)d_in[8];
  const float* W2e  = (const float*)d_in[9];
  const float* att2 = (const float*)d_in[10];
  const float* b2   = (const float*)d_in[11];
  const int*   ei   = (const int*)d_in[12];
  float* out = (float*)d_out;

  char* w = (char*)d_ws;
  size_t off = 0;
  auto alloc = [&](size_t bytes) -> char* {
    char* p = w + off;
    off = (off + bytes + 255) & ~(size_t)255;
    return p;
  };
  // ---- zero zone (memset every call) ----
  float*    meanacc = (float*)alloc(16);
  unsigned* redmax  = (unsigned*)alloc(8);
  float*    redsum  = (float*)((char*)redmax + 4);
  int*      deg     = (int*)alloc((size_t)N_NODESC * 4);
  size_t zero_bytes = off;
  // ---- rest ----
  int*   offsets = (int*)alloc((size_t)(N_NODESC + 1) * 4);
  int*   cursor  = (int*)alloc((size_t)N_NODESC * 4);
  int*   srcp    = (int*)alloc((size_t)E_TOTC * 4);
  float4* rec    = (float4*)alloc((size_t)E_TOTC * 16);
  float* ef2     = (float*)alloc((size_t)E_TOTC * 4);
  float* sl      = (float*)alloc((size_t)N_NODESC * 4);
  float* sr      = (float*)alloc((size_t)N_NODESC * 4);
  float* scores  = (float*)alloc((size_t)N_NODESC * 4);
  unsigned short* xb    = (unsigned short*)alloc((size_t)MPAD * IN_DIMC * 2);
  unsigned short* Bfrag = (unsigned short*)alloc((size_t)2 * 128 * 256 * 2);
  unsigned short* xl    = (unsigned short*)alloc((size_t)MPAD * FDIM * 2);
  unsigned short* xr    = (unsigned short*)alloc((size_t)MPAD * FDIM * 2);
  (void)ws_size; (void)in_sizes; (void)n_in; (void)out_size;

  hipMemsetAsync(d_ws, 0, zero_bytes, stream);

  k_mean  <<<400, 256, 0, stream>>>(ea, meanacc);
  k_cvtx  <<<(int)(((size_t)MPAD * IN_DIMC / 4 + 255) / 256), 256, 0, stream>>>(x, xb);
  k_cvtw  <<<256, 256, 0, stream>>>(W1l, W1r, Bfrag);
  k_count <<<(E_TOTC + 255) / 256, 256, 0, stream>>>(ei, deg);
  k_scan  <<<1, 1024, 0, stream>>>(deg, offsets, cursor);
  k_scatter<<<(E_TOTC + 255) / 256, 256, 0, stream>>>(ei, ea, meanacc, W2e,
                                                      cursor, srcp, rec, ef2);
  {
    dim3 g(MPAD / 32, 2);
    k_gemm_mfma<<<g, 256, 0, stream>>>(xb, Bfrag, xl, xr);
  }
  k_attn1 <<<N_NODESC, 256, 0, stream>>>(offsets, rec, xl, xr,
                                         W1e, att1, b1, W2l, W2r, sl, sr);
  k_attn2 <<<(N_NODESC + 3) / 4, 256, 0, stream>>>(offsets, srcp, ef2, att2, b2,
                                                   sl, sr, scores, out);
  k_smax_max <<<256, 256, 0, stream>>>(scores, redmax);
  k_smax_sum <<<256, 256, 0, stream>>>(scores, redmax, redsum);
  k_smax_write<<<(N_NODESC + 255) / 256, 256, 0, stream>>>(scores, redmax, redsum, out);
}

// Round 2
// 459.714 us; speedup vs baseline: 1.3313x; 1.1486x over previous
//
#include <hip/hip_runtime.h>
#include <hip/hip_bf16.h>

typedef __hip_bfloat16 bf16;
typedef __attribute__((ext_vector_type(8))) short short8;
typedef __attribute__((ext_vector_type(4))) float floatx4;
typedef __attribute__((ext_vector_type(4))) unsigned short ushortx4;

#define N_NODESC 50000
#define MPAD     50016     // padded to 32-row tiles
#define N_EDGESC 800000
#define E_TOTC   850000    // + self loops
#define IN_DIMC  128
#define FDIM     256       // HEADS*HID
#define HEADSC   4
#define HIDC     64
#define NEG_SLOPE 0.2f
#define RESCALE_THR 8.0f

__device__ __forceinline__ float bits2f(unsigned short b){
  return __uint_as_float(((unsigned)b) << 16);
}

__device__ __forceinline__ float wave_sum(float v){
  #pragma unroll
  for (int m = 32; m > 0; m >>= 1) v += __shfl_xor(v, m, 64);
  return v;
}
__device__ __forceinline__ float wave_max(float v){
  #pragma unroll
  for (int m = 32; m > 0; m >>= 1) v = fmaxf(v, __shfl_xor(v, m, 64));
  return v;
}

// ---------- edge_attr column means (for self-loop fill) ----------
__global__ __launch_bounds__(256) void k_mean(const float* __restrict__ ea,
                                              float* __restrict__ meanacc){
  float s0 = 0.f, s1 = 0.f, s2 = 0.f;
  for (int i = blockIdx.x * blockDim.x + threadIdx.x; i < N_EDGESC;
       i += gridDim.x * blockDim.x){
    s0 += ea[i*3+0]; s1 += ea[i*3+1]; s2 += ea[i*3+2];
  }
  s0 = wave_sum(s0); s1 = wave_sum(s1); s2 = wave_sum(s2);
  __shared__ float red[3][4];
  int lane = threadIdx.x & 63, w = threadIdx.x >> 6;
  if (lane == 0){ red[0][w] = s0; red[1][w] = s1; red[2][w] = s2; }
  __syncthreads();
  if (threadIdx.x == 0){
    float t0 = 0.f, t1 = 0.f, t2 = 0.f;
    for (int i = 0; i < 4; i++){ t0 += red[0][i]; t1 += red[1][i]; t2 += red[2][i]; }
    atomicAdd(&meanacc[0], t0); atomicAdd(&meanacc[1], t1); atomicAdd(&meanacc[2], t2);
  }
}

// ---------- convert x (fp32) -> xb (bf16 bits), zero pad rows ----------
__global__ __launch_bounds__(256) void k_cvtx(const float* __restrict__ x,
                                              unsigned short* __restrict__ xb){
  size_t tid = (size_t)blockIdx.x * 256 + threadIdx.x;
  size_t base = tid * 4;
  const size_t NELEM = (size_t)N_NODESC * IN_DIMC;   // 6,400,000
  ushortx4 o;
  if (base + 3 < NELEM){
    const float4* xp = (const float4*)(x + base);
    float4 v = *xp;
    o[0] = (unsigned short)(__float_as_uint(v.x) >> 16);
    o[1] = (unsigned short)(__float_as_uint(v.y) >> 16);
    o[2] = (unsigned short)(__float_as_uint(v.z) >> 16);
    o[3] = (unsigned short)(__float_as_uint(v.w) >> 16);
  } else {
    #pragma unroll
    for (int f = 0; f < 4; f++){
      size_t i = base + f;
      float v = (i < NELEM) ? x[i] : 0.f;
      o[f] = (unsigned short)(__float_as_uint(v) >> 16);
    }
  }
  *(ushortx4*)(xb + base) = o;
}

// ---------- convert W1l,W1r -> MFMA-frag-contiguous bf16 layout ----------
// out[mat][kblk(16)][n(256)][j(8)] = W[kblk*8+j][n]
__global__ __launch_bounds__(256) void k_cvtw(const float* __restrict__ W1l,
                                              const float* __restrict__ W1r,
                                              unsigned short* __restrict__ Bfrag){
  int idx = blockIdx.x * 256 + threadIdx.x;   // < 65536
  int mat = idx >> 15;
  int r   = idx & 32767;       // k*256+n
  int k   = r >> 8, n = r & 255;
  float v = mat ? W1r[r] : W1l[r];
  int pos = (mat << 15) + (((k >> 3) << 8) + n) * 8 + (k & 7);
  Bfrag[pos] = (unsigned short)(__float_as_uint(v) >> 16);
}

// ---------- MFMA dual GEMM: xl = x@W1l, xr = x@W1r (bf16 out) ----------
__global__ __launch_bounds__(256) void k_gemm_mfma(const unsigned short* __restrict__ xb,
                                                   const unsigned short* __restrict__ Bfrag,
                                                   unsigned short* __restrict__ xl,
                                                   unsigned short* __restrict__ xr){
  const int mat = blockIdx.y;
  const int r0  = blockIdx.x * 32;
  const int w = threadIdx.x >> 6, lane = threadIdx.x & 63;
  const int quad = lane >> 4, l16 = lane & 15;
  const unsigned short* Bm = Bfrag + ((size_t)mat << 15);
  unsigned short* C = mat ? xr : xl;

  short8 afr[2][4];
  #pragma unroll
  for (int ms = 0; ms < 2; ms++)
    #pragma unroll
    for (int ks = 0; ks < 4; ks++){
      const unsigned short* p = xb + (size_t)(r0 + ms*16 + l16) * IN_DIMC + ks*32 + quad*8;
      afr[ms][ks] = *reinterpret_cast<const short8*>(p);
    }
  const int n0 = w * 64;
  floatx4 acc[2][4];
  #pragma unroll
  for (int ms = 0; ms < 2; ms++)
    #pragma unroll
    for (int ns = 0; ns < 4; ns++){
      floatx4 z = {0.f, 0.f, 0.f, 0.f};
      acc[ms][ns] = z;
    }
  #pragma unroll
  for (int ks = 0; ks < 4; ks++){
    #pragma unroll
    for (int ns = 0; ns < 4; ns++){
      int n = n0 + ns*16 + l16;
      int kblk = ks*4 + quad;
      short8 bfr = *reinterpret_cast<const short8*>(Bm + ((size_t)kblk*256 + n)*8);
      acc[0][ns] = __builtin_amdgcn_mfma_f32_16x16x32_bf16(afr[0][ks], bfr, acc[0][ns], 0, 0, 0);
      acc[1][ns] = __builtin_amdgcn_mfma_f32_16x16x32_bf16(afr[1][ks], bfr, acc[1][ns], 0, 0, 0);
    }
  }
  #pragma unroll
  for (int ms = 0; ms < 2; ms++)
    #pragma unroll
    for (int ns = 0; ns < 4; ns++){
      int col = n0 + ns*16 + l16;
      #pragma unroll
      for (int rg = 0; rg < 4; rg++){
        int row = r0 + ms*16 + quad*4 + rg;
        C[(size_t)row * FDIM + col] = (unsigned short)(__float_as_uint(acc[ms][ns][rg]) >> 16);
      }
    }
}

// ---------- CSR build: count, scan, scatter ----------
__global__ __launch_bounds__(256) void k_count(const int* __restrict__ ei,
                                               int* __restrict__ deg){
  int e = blockIdx.x * blockDim.x + threadIdx.x;
  if (e >= E_TOTC) return;
  int dst = (e < N_EDGESC) ? ei[N_EDGESC + e] : (e - N_EDGESC);
  atomicAdd(&deg[dst], 1);
}

__global__ __launch_bounds__(1024) void k_scan(const int* __restrict__ deg,
                                               int* __restrict__ offsets,
                                               int* __restrict__ cursor){
  const int n = N_NODESC;
  const int T = 1024;
  const int CH = (n + T - 1) / T;
  int t = threadIdx.x;
  int beg = t * CH, end = min(beg + CH, n);
  int s = 0;
  for (int i = beg; i < end; i++) s += deg[i];
  __shared__ int sums[1024];
  sums[t] = s;
  __syncthreads();
  for (int off = 1; off < T; off <<= 1){
    int v = (t >= off) ? sums[t - off] : 0;
    __syncthreads();
    sums[t] += v;
    __syncthreads();
  }
  int run = sums[t] - s;
  for (int i = beg; i < end; i++){
    offsets[i] = run; cursor[i] = run; run += deg[i];
  }
  if (t == T - 1) offsets[n] = sums[T - 1];
}

// packed edge record: .x = src (int bits), .y/.z/.w = edge_attr
__global__ __launch_bounds__(256) void k_scatter(const int* __restrict__ ei,
                                                 const float* __restrict__ ea,
                                                 const float* __restrict__ meanacc,
                                                 int* __restrict__ cursor,
                                                 float4* __restrict__ rec){
  int e = blockIdx.x * blockDim.x + threadIdx.x;
  if (e >= E_TOTC) return;
  int src, dst; float e0, e1, e2;
  if (e < N_EDGESC){
    src = ei[e]; dst = ei[N_EDGESC + e];
    e0 = ea[e*3+0]; e1 = ea[e*3+1]; e2 = ea[e*3+2];
  } else {
    src = dst = e - N_EDGESC;
    const float inv = 1.0f / (float)N_EDGESC;
    e0 = meanacc[0]*inv; e1 = meanacc[1]*inv; e2 = meanacc[2]*inv;
  }
  int pos = atomicAdd(&cursor[dst], 1);
  float4 r; r.x = __int_as_float(src); r.y = e0; r.z = e1; r.w = e2;
  rec[pos] = r;
}

// ---------- layer-1 FUSED: one wave per node, single pass, zero LDS ----------
// lane owns features f0..f0+3 (head = lane>>4); deferred-max online softmax
// entirely in registers; 2-deep pipeline on (edge record, xl gather).
__global__ __launch_bounds__(256, 8) void k_attn1(const int* __restrict__ offsets,
                                                  const float4* __restrict__ rec,
                                                  const unsigned short* __restrict__ xl,
                                                  const unsigned short* __restrict__ xr,
                                                  const float* __restrict__ W1e,
                                                  const float* __restrict__ att1,
                                                  const float* __restrict__ b1,
                                                  const float* __restrict__ W2l,
                                                  const float* __restrict__ W2r,
                                                  float* __restrict__ sl,
                                                  float* __restrict__ sr){
  const int t = threadIdx.x, lane = t & 63, w = t >> 6;
  const int n = blockIdx.x * 4 + w;
  const int f0 = lane * 4;

  // per-wave invariants in registers
  float xrv[4], w0[4], w1[4], w2[4], av[4];
  {
    ushortx4 xw = *(const ushortx4*)(xr + (size_t)n * FDIM + f0);
    float4 a = *(const float4*)(W1e + f0);
    float4 b = *(const float4*)(W1e + FDIM + f0);
    float4 c = *(const float4*)(W1e + 2*FDIM + f0);
    float4 d = *(const float4*)(att1 + f0);
    xrv[0]=bits2f(xw[0]); xrv[1]=bits2f(xw[1]); xrv[2]=bits2f(xw[2]); xrv[3]=bits2f(xw[3]);
    w0[0]=a.x; w0[1]=a.y; w0[2]=a.z; w0[3]=a.w;
    w1[0]=b.x; w1[1]=b.y; w1[2]=b.z; w1[3]=b.w;
    w2[0]=c.x; w2[1]=c.y; w2[2]=c.z; w2[3]=c.w;
    av[0]=d.x; av[1]=d.y; av[2]=d.z; av[3]=d.w;
  }
  const int beg = offsets[n], end = offsets[n + 1];
  const int last = end - 1;

  float m = -1e30f, den = 0.f;
  float acc0 = 0.f, acc1 = 0.f, acc2 = 0.f, acc3 = 0.f;

  // 2-deep pipeline prologue
  float4 rc  = rec[beg];
  float4 rcn = rec[min(beg + 1, last)];
  int src0 = __builtin_amdgcn_readfirstlane(__float_as_int(rc.x));
  ushortx4 raw = *(const ushortx4*)(xl + (size_t)src0 * FDIM + f0);

  for (int j = beg; j < end; j++){
    const float e0 = rc.y, e1 = rc.z, e2 = rc.w;
    // issue next gather (record already resident)
    int srcn = __builtin_amdgcn_readfirstlane(__float_as_int(rcn.x));
    ushortx4 rawn = *(const ushortx4*)(xl + (size_t)srcn * FDIM + f0);
    rc = rcn;
    // issue record load 2 ahead
    rcn = rec[min(j + 2, last)];

    // elementwise + per-head logit partial (4 features)
    float xv0 = bits2f(raw[0]), xv1 = bits2f(raw[1]);
    float xv2 = bits2f(raw[2]), xv3 = bits2f(raw[3]);
    float v0 = xv0 + xrv[0] + e0*w0[0] + e1*w1[0] + e2*w2[0];
    float v1 = xv1 + xrv[1] + e0*w0[1] + e1*w1[1] + e2*w2[1];
    float v2 = xv2 + xrv[2] + e0*w0[2] + e1*w1[2] + e2*w2[2];
    float v3 = xv3 + xrv[3] + e0*w0[3] + e1*w1[3] + e2*w2[3];
    v0 = fmaxf(v0, NEG_SLOPE * v0);
    v1 = fmaxf(v1, NEG_SLOPE * v1);
    v2 = fmaxf(v2, NEG_SLOPE * v2);
    v3 = fmaxf(v3, NEG_SLOPE * v3);
    float pp = v0*av[0] + v1*av[1] + v2*av[2] + v3*av[3];
    // 16-lane (per-head) reduce
    pp += __shfl_xor(pp, 1, 64);
    pp += __shfl_xor(pp, 2, 64);
    pp += __shfl_xor(pp, 4, 64);
    pp += __shfl_xor(pp, 8, 64);

    // deferred-max online softmax (rescale fires ~ln(deg) times per node)
    if (pp > m + RESCALE_THR){
      float corr = __expf(m - pp);
      den *= corr;
      acc0 *= corr; acc1 *= corr; acc2 *= corr; acc3 *= corr;
      m = pp;
    }
    float al = __expf(pp - m);
    den += al;
    acc0 += al * xv0; acc1 += al * xv1; acc2 += al * xv2; acc3 += al * xv3;

    raw = rawn;
  }

  // epilogue: h = acc/den + b1, ELU, project onto W2l/W2r
  float invd = 1.0f / den;
  float4 bb = *(const float4*)(b1 + f0);
  float h0 = acc0 * invd + bb.x;
  float h1 = acc1 * invd + bb.y;
  float h2 = acc2 * invd + bb.z;
  float h3 = acc3 * invd + bb.w;
  h0 = (h0 > 0.f) ? h0 : (__expf(h0) - 1.f);
  h1 = (h1 > 0.f) ? h1 : (__expf(h1) - 1.f);
  h2 = (h2 > 0.f) ? h2 : (__expf(h2) - 1.f);
  h3 = (h3 > 0.f) ? h3 : (__expf(h3) - 1.f);
  float4 wl = *(const float4*)(W2l + f0);
  float4 wr = *(const float4*)(W2r + f0);
  float pa = h0*wl.x + h1*wl.y + h2*wl.z + h3*wl.w;
  float pb = h0*wr.x + h1*wr.y + h2*wr.z + h3*wr.w;
  pa = wave_sum(pa);
  pb = wave_sum(pb);
  if (lane == 0){ sl[n] = pa; sr[n] = pb; }
}

// ---------- layer-2 FUSED: edge logits + online softmax -> scores ----------
__global__ __launch_bounds__(256) void k_attn2(const int* __restrict__ offsets,
                                               const float4* __restrict__ rec,
                                               const float* __restrict__ W2e,
                                               const float* __restrict__ att2,
                                               const float* __restrict__ b2p,
                                               const float* __restrict__ sl,
                                               const float* __restrict__ sr,
                                               float* __restrict__ scores,
                                               float* __restrict__ out){
  int t = threadIdx.x, lane = t & 63;
  int n = blockIdx.x * 4 + (t >> 6);
  if (n >= N_NODESC) return;
  const float attv = att2[0];
  const float w2e0 = W2e[0], w2e1 = W2e[1], w2e2 = W2e[2];
  const float srn = sr[n];
  int beg = offsets[n], end = offsets[n + 1];
  float m = -1e30f, den = 0.f, num = 0.f;
  for (int j = beg + lane; j < end; j += 64){
    float4 rc = rec[j];
    float slv = sl[__float_as_int(rc.x)];
    float v = slv + srn + rc.y*w2e0 + rc.z*w2e1 + rc.w*w2e2;
    v = (v > 0.f) ? v : NEG_SLOPE * v;
    float lg = v * attv;
    float mn = fmaxf(m, lg);
    float corr = __expf(m - mn);
    float pe   = __expf(lg - mn);
    den = den * corr + pe;
    num = num * corr + pe * slv;
    m = mn;
  }
  float mg = wave_max(m);
  float scale = __expf(m - mg);
  float deng = wave_sum(den * scale);
  float numg = wave_sum(num * scale);
  if (lane == 0){
    float s = numg / deng + b2p[0];
    scores[n] = s;
    out[N_NODESC + n] = s;
  }
}

// ---------- global softmax over scores ----------
__device__ __forceinline__ unsigned fkey(float f){
  unsigned u = __float_as_uint(f);
  return u ^ ((u >> 31) ? 0xFFFFFFFFu : 0x80000000u);
}
__device__ __forceinline__ float funkey(unsigned k){
  unsigned u = (k >> 31) ? (k ^ 0x80000000u) : ~k;
  return __uint_as_float(u);
}

__global__ __launch_bounds__(256) void k_smax_max(const float* __restrict__ scores,
                                                  unsigned* __restrict__ redmax){
  float m = -1e30f;
  for (int i = blockIdx.x * blockDim.x + threadIdx.x; i < N_NODESC;
       i += gridDim.x * blockDim.x)
    m = fmaxf(m, scores[i]);
  m = wave_max(m);
  __shared__ float ws_[4];
  int lane = threadIdx.x & 63, w = threadIdx.x >> 6;
  if (lane == 0) ws_[w] = m;
  __syncthreads();
  if (threadIdx.x == 0){
    for (int i = 1; i < 4; i++) m = fmaxf(m, ws_[i]);
    atomicMax(redmax, fkey(m));
  }
}

__global__ __launch_bounds__(256) void k_smax_sum(const float* __restrict__ scores,
                                                  const unsigned* __restrict__ redmax,
                                                  float* __restrict__ redsum){
  float mx = funkey(*redmax);
  float s = 0.f;
  for (int i = blockIdx.x * blockDim.x + threadIdx.x; i < N_NODESC;
       i += gridDim.x * blockDim.x)
    s += __expf(scores[i] - mx);
  s = wave_sum(s);
  __shared__ float ws_[4];
  int lane = threadIdx.x & 63, w = threadIdx.x >> 6;
  if (lane == 0) ws_[w] = s;
  __syncthreads();
  if (threadIdx.x == 0){
    float t = 0.f;
    for (int i = 0; i < 4; i++) t += ws_[i];
    atomicAdd(redsum, t);
  }
}

__global__ __launch_bounds__(256) void k_smax_write(const float* __restrict__ scores,
                                                    const unsigned* __restrict__ redmax,
                                                    const float* __restrict__ redsum,
                                                    float* __restrict__ out){
  int i = blockIdx.x * blockDim.x + threadIdx.x;
  if (i >= N_NODESC) return;
  float mx = funkey(*redmax);
  float inv = 1.0f / (*redsum);
  out[i] = __expf(scores[i] - mx) * inv;
}

extern "C" void kernel_launch(void* const* d_in, const int* in_sizes, int n_in,
                              void* d_out, int out_size, void* d_ws, size_t ws_size,
                              hipStream_t stream) {
  const float* x    = (const float*)d_in[0];
  const float* ea   = (const float*)d_in[1];
  const float* W1l  = (const float*)d_in[2];
  const float* W1r  = (const float*)d_in[3];
  const float* W1e  = (const float*)d_in[4];
  const float* att1 = (const float*)d_in[5];
  const float* b1   = (const float*)d_in[6];
  const float* W2l  = (const float*)d_in[7];
  const float* W2r  = (const float*)d_in[8];
  const float* W2e  = (const float*)d_in[9];
  const float* att2 = (const float*)d_in[10];
  const float* b2   = (const float*)d_in[11];
  const int*   ei   = (const int*)d_in[12];
  float* out = (float*)d_out;

  char* w = (char*)d_ws;
  size_t off = 0;
  auto alloc = [&](size_t bytes) -> char* {
    char* p = w + off;
    off = (off + bytes + 255) & ~(size_t)255;
    return p;
  };
  // ---- zero zone (memset every call) ----
  float*    meanacc = (float*)alloc(16);
  unsigned* redmax  = (unsigned*)alloc(8);
  float*    redsum  = (float*)((char*)redmax + 4);
  int*      deg     = (int*)alloc((size_t)N_NODESC * 4);
  size_t zero_bytes = off;
  // ---- rest ----
  int*   offsets = (int*)alloc((size_t)(N_NODESC + 1) * 4);
  int*   cursor  = (int*)alloc((size_t)N_NODESC * 4);
  float4* rec    = (float4*)alloc((size_t)E_TOTC * 16);
  float* sl      = (float*)alloc((size_t)N_NODESC * 4);
  float* sr      = (float*)alloc((size_t)N_NODESC * 4);
  float* scores  = (float*)alloc((size_t)N_NODESC * 4);
  unsigned short* xb    = (unsigned short*)alloc((size_t)MPAD * IN_DIMC * 2);
  unsigned short* Bfrag = (unsigned short*)alloc((size_t)2 * 128 * 256 * 2);
  unsigned short* xl    = (unsigned short*)alloc((size_t)MPAD * FDIM * 2);
  unsigned short* xr    = (unsigned short*)alloc((size_t)MPAD * FDIM * 2);
  (void)ws_size; (void)in_sizes; (void)n_in; (void)out_size;

  hipMemsetAsync(d_ws, 0, zero_bytes, stream);

  k_mean  <<<400, 256, 0, stream>>>(ea, meanacc);
  k_cvtx  <<<(int)(((size_t)MPAD * IN_DIMC / 4 + 255) / 256), 256, 0, stream>>>(x, xb);
  k_cvtw  <<<256, 256, 0, stream>>>(W1l, W1r, Bfrag);
  k_count <<<(E_TOTC + 255) / 256, 256, 0, stream>>>(ei, deg);
  k_scan  <<<1, 1024, 0, stream>>>(deg, offsets, cursor);
  k_scatter<<<(E_TOTC + 255) / 256, 256, 0, stream>>>(ei, ea, meanacc, cursor, rec);
  {
    dim3 g(MPAD / 32, 2);
    k_gemm_mfma<<<g, 256, 0, stream>>>(xb, Bfrag, xl, xr);
  }
  k_attn1 <<<N_NODESC / 4, 256, 0, stream>>>(offsets, rec, xl, xr,
                                             W1e, att1, b1, W2l, W2r, sl, sr);
  k_attn2 <<<(N_NODESC + 3) / 4, 256, 0, stream>>>(offsets, rec, W2e, att2, b2,
                                                   sl, sr, scores, out);
  k_smax_max <<<256, 256, 0, stream>>>(scores, redmax);
  k_smax_sum <<<256, 256, 0, stream>>>(scores, redmax, redsum);
  k_smax_write<<<(N_NODESC + 255) / 256, 256, 0, stream>>>(scores, redmax, redsum, out);
}

// Round 3
// 366.978 us; speedup vs baseline: 1.6677x; 1.2527x over previous
//
#include <hip/hip_runtime.h>
#include <hip/hip_bf16.h>

typedef __hip_bfloat16 bf16;
typedef __attribute__((ext_vector_type(8))) short short8;
typedef __attribute__((ext_vector_type(4))) float floatx4;
typedef __attribute__((ext_vector_type(4))) unsigned short ushortx4;

#define N_NODESC 50000
#define MPAD     50016     // padded to 32-row tiles
#define N_EDGESC 800000
#define E_TOTC   850000    // + self loops
#define IN_DIMC  128
#define FDIM     256       // HEADS*HID
#define HEADSC   4
#define HIDC     64
#define NEG_SLOPE 0.2f
#define RESCALE_THR 8.0f

#define SCAN_TILE 1024
#define SCAN_NB   ((N_NODESC + SCAN_TILE - 1) / SCAN_TILE)   // 49

__device__ __forceinline__ float bits2f(unsigned short b){
  return __uint_as_float(((unsigned)b) << 16);
}

__device__ __forceinline__ float wave_sum(float v){
  #pragma unroll
  for (int m = 32; m > 0; m >>= 1) v += __shfl_xor(v, m, 64);
  return v;
}
__device__ __forceinline__ float wave_max(float v){
  #pragma unroll
  for (int m = 32; m > 0; m >>= 1) v = fmaxf(v, __shfl_xor(v, m, 64));
  return v;
}

// ---------- edge_attr column means (for self-loop fill) ----------
__global__ __launch_bounds__(256) void k_mean(const float* __restrict__ ea,
                                              float* __restrict__ meanacc){
  float s0 = 0.f, s1 = 0.f, s2 = 0.f;
  for (int i = blockIdx.x * blockDim.x + threadIdx.x; i < N_EDGESC;
       i += gridDim.x * blockDim.x){
    s0 += ea[i*3+0]; s1 += ea[i*3+1]; s2 += ea[i*3+2];
  }
  s0 = wave_sum(s0); s1 = wave_sum(s1); s2 = wave_sum(s2);
  __shared__ float red[3][4];
  int lane = threadIdx.x & 63, w = threadIdx.x >> 6;
  if (lane == 0){ red[0][w] = s0; red[1][w] = s1; red[2][w] = s2; }
  __syncthreads();
  if (threadIdx.x == 0){
    float t0 = 0.f, t1 = 0.f, t2 = 0.f;
    for (int i = 0; i < 4; i++){ t0 += red[0][i]; t1 += red[1][i]; t2 += red[2][i]; }
    atomicAdd(&meanacc[0], t0); atomicAdd(&meanacc[1], t1); atomicAdd(&meanacc[2], t2);
  }
}

// ---------- convert x (fp32) -> xb (bf16 bits), zero pad rows ----------
__global__ __launch_bounds__(256) void k_cvtx(const float* __restrict__ x,
                                              unsigned short* __restrict__ xb){
  size_t tid = (size_t)blockIdx.x * 256 + threadIdx.x;
  size_t base = tid * 4;
  const size_t NELEM = (size_t)N_NODESC * IN_DIMC;   // 6,400,000
  ushortx4 o;
  if (base + 3 < NELEM){
    const float4* xp = (const float4*)(x + base);
    float4 v = *xp;
    o[0] = (unsigned short)(__float_as_uint(v.x) >> 16);
    o[1] = (unsigned short)(__float_as_uint(v.y) >> 16);
    o[2] = (unsigned short)(__float_as_uint(v.z) >> 16);
    o[3] = (unsigned short)(__float_as_uint(v.w) >> 16);
  } else {
    #pragma unroll
    for (int f = 0; f < 4; f++){
      size_t i = base + f;
      float v = (i < NELEM) ? x[i] : 0.f;
      o[f] = (unsigned short)(__float_as_uint(v) >> 16);
    }
  }
  *(ushortx4*)(xb + base) = o;
}

// ---------- convert W1l,W1r -> MFMA-frag-contiguous bf16 layout ----------
// out[mat][kblk(16)][n(256)][j(8)] = W[kblk*8+j][n]
__global__ __launch_bounds__(256) void k_cvtw(const float* __restrict__ W1l,
                                              const float* __restrict__ W1r,
                                              unsigned short* __restrict__ Bfrag){
  int idx = blockIdx.x * 256 + threadIdx.x;   // < 65536
  int mat = idx >> 15;
  int r   = idx & 32767;       // k*256+n
  int k   = r >> 8, n = r & 255;
  float v = mat ? W1r[r] : W1l[r];
  int pos = (mat << 15) + (((k >> 3) << 8) + n) * 8 + (k & 7);
  Bfrag[pos] = (unsigned short)(__float_as_uint(v) >> 16);
}

// ---------- MFMA dual GEMM: xl = x@W1l, xr = x@W1r (bf16 out) ----------
__global__ __launch_bounds__(256) void k_gemm_mfma(const unsigned short* __restrict__ xb,
                                                   const unsigned short* __restrict__ Bfrag,
                                                   unsigned short* __restrict__ xl,
                                                   unsigned short* __restrict__ xr){
  const int mat = blockIdx.y;
  const int r0  = blockIdx.x * 32;
  const int w = threadIdx.x >> 6, lane = threadIdx.x & 63;
  const int quad = lane >> 4, l16 = lane & 15;
  const unsigned short* Bm = Bfrag + ((size_t)mat << 15);
  unsigned short* C = mat ? xr : xl;

  short8 afr[2][4];
  #pragma unroll
  for (int ms = 0; ms < 2; ms++)
    #pragma unroll
    for (int ks = 0; ks < 4; ks++){
      const unsigned short* p = xb + (size_t)(r0 + ms*16 + l16) * IN_DIMC + ks*32 + quad*8;
      afr[ms][ks] = *reinterpret_cast<const short8*>(p);
    }
  const int n0 = w * 64;
  floatx4 acc[2][4];
  #pragma unroll
  for (int ms = 0; ms < 2; ms++)
    #pragma unroll
    for (int ns = 0; ns < 4; ns++){
      floatx4 z = {0.f, 0.f, 0.f, 0.f};
      acc[ms][ns] = z;
    }
  #pragma unroll
  for (int ks = 0; ks < 4; ks++){
    #pragma unroll
    for (int ns = 0; ns < 4; ns++){
      int n = n0 + ns*16 + l16;
      int kblk = ks*4 + quad;
      short8 bfr = *reinterpret_cast<const short8*>(Bm + ((size_t)kblk*256 + n)*8);
      acc[0][ns] = __builtin_amdgcn_mfma_f32_16x16x32_bf16(afr[0][ks], bfr, acc[0][ns], 0, 0, 0);
      acc[1][ns] = __builtin_amdgcn_mfma_f32_16x16x32_bf16(afr[1][ks], bfr, acc[1][ns], 0, 0, 0);
    }
  }
  #pragma unroll
  for (int ms = 0; ms < 2; ms++)
    #pragma unroll
    for (int ns = 0; ns < 4; ns++){
      int col = n0 + ns*16 + l16;
      #pragma unroll
      for (int rg = 0; rg < 4; rg++){
        int row = r0 + ms*16 + quad*4 + rg;
        C[(size_t)row * FDIM + col] = (unsigned short)(__float_as_uint(acc[ms][ns][rg]) >> 16);
      }
    }
}

// ---------- CSR build: count, 3-phase scan, scatter ----------
__global__ __launch_bounds__(256) void k_count(const int* __restrict__ ei,
                                               int* __restrict__ deg){
  int e = blockIdx.x * blockDim.x + threadIdx.x;
  if (e >= E_TOTC) return;
  int dst = (e < N_EDGESC) ? ei[N_EDGESC + e] : (e - N_EDGESC);
  atomicAdd(&deg[dst], 1);
}

// phase A: per-block (1024-elem tile) local exclusive prescan + block totals
__global__ __launch_bounds__(256) void k_scan_pa(const int* __restrict__ deg,
                                                 int* __restrict__ pre,
                                                 int* __restrict__ bsum){
  int b = blockIdx.x, t = threadIdx.x;
  int lane = t & 63, w = t >> 6;
  int base = b * SCAN_TILE + t * 4;
  int4 v = {0, 0, 0, 0};
  if (base + 3 < N_NODESC){
    v = *(const int4*)(deg + base);
  } else {
    if (base + 0 < N_NODESC) v.x = deg[base + 0];
    if (base + 1 < N_NODESC) v.y = deg[base + 1];
    if (base + 2 < N_NODESC) v.z = deg[base + 2];
    if (base + 3 < N_NODESC) v.w = deg[base + 3];
  }
  int s = v.x + v.y + v.z + v.w;
  int inc = s;
  #pragma unroll
  for (int off = 1; off < 64; off <<= 1){
    int u = __shfl_up(inc, off, 64);
    if (lane >= off) inc += u;
  }
  __shared__ int wsum[4];
  if (lane == 63) wsum[w] = inc;
  __syncthreads();
  int wadd = 0;
  #pragma unroll
  for (int i = 0; i < 4; i++) if (i < w) wadd += wsum[i];
  int excl = inc - s + wadd;
  if (base + 3 < N_NODESC){
    int4 o;
    o.x = excl; o.y = o.x + v.x; o.z = o.y + v.y; o.w = o.z + v.z;
    *(int4*)(pre + base) = o;
  } else {
    int run = excl;
    if (base + 0 < N_NODESC){ pre[base + 0] = run; run += v.x; }
    if (base + 1 < N_NODESC){ pre[base + 1] = run; run += v.y; }
    if (base + 2 < N_NODESC){ pre[base + 2] = run; run += v.z; }
    if (base + 3 < N_NODESC){ pre[base + 3] = run; }
  }
  if (t == 255) bsum[b] = wsum[0] + wsum[1] + wsum[2] + wsum[3];
}

// phase B: one wave scans the block totals
__global__ __launch_bounds__(64) void k_scan_pb(const int* __restrict__ bsum,
                                                int* __restrict__ boff,
                                                int* __restrict__ offsets){
  int lane = threadIdx.x;
  int s = (lane < SCAN_NB) ? bsum[lane] : 0;
  int inc = s;
  #pragma unroll
  for (int off = 1; off < 64; off <<= 1){
    int u = __shfl_up(inc, off, 64);
    if (lane >= off) inc += u;
  }
  if (lane < SCAN_NB) boff[lane] = inc - s;
  if (lane == 63) offsets[N_NODESC] = inc;   // grand total (= E_TOTC)
}

// phase C: add block offset, emit offsets + cursor
__global__ __launch_bounds__(256) void k_scan_pc(const int* __restrict__ pre,
                                                 const int* __restrict__ boff,
                                                 int* __restrict__ offsets,
                                                 int* __restrict__ cursor){
  int b = blockIdx.x;
  int base = b * SCAN_TILE + threadIdx.x * 4;
  int add = boff[b];
  if (base + 3 < N_NODESC){
    int4 p = *(const int4*)(pre + base);
    p.x += add; p.y += add; p.z += add; p.w += add;
    *(int4*)(offsets + base) = p;
    *(int4*)(cursor + base) = p;
  } else {
    #pragma unroll
    for (int f = 0; f < 4; f++){
      int i = base + f;
      if (i < N_NODESC){ int vv = pre[i] + add; offsets[i] = vv; cursor[i] = vv; }
    }
  }
}

// packed edge record: .x = src (int bits), .y/.z/.w = edge_attr
__global__ __launch_bounds__(256) void k_scatter(const int* __restrict__ ei,
                                                 const float* __restrict__ ea,
                                                 const float* __restrict__ meanacc,
                                                 int* __restrict__ cursor,
                                                 float4* __restrict__ rec){
  int e = blockIdx.x * blockDim.x + threadIdx.x;
  if (e >= E_TOTC) return;
  int src, dst; float e0, e1, e2;
  if (e < N_EDGESC){
    src = ei[e]; dst = ei[N_EDGESC + e];
    e0 = ea[e*3+0]; e1 = ea[e*3+1]; e2 = ea[e*3+2];
  } else {
    src = dst = e - N_EDGESC;
    const float inv = 1.0f / (float)N_EDGESC;
    e0 = meanacc[0]*inv; e1 = meanacc[1]*inv; e2 = meanacc[2]*inv;
  }
  int pos = atomicAdd(&cursor[dst], 1);
  float4 r; r.x = __int_as_float(src); r.y = e0; r.z = e1; r.w = e2;
  rec[pos] = r;
}

// ---------- layer-1 FUSED: one wave per node, single pass, zero LDS ----------
// lane owns features f0..f0+3 (head = lane>>4); deferred-max online softmax
// entirely in registers; 2-deep pipeline on (edge record, xl gather).
__global__ __launch_bounds__(256, 8) void k_attn1(const int* __restrict__ offsets,
                                                  const float4* __restrict__ rec,
                                                  const unsigned short* __restrict__ xl,
                                                  const unsigned short* __restrict__ xr,
                                                  const float* __restrict__ W1e,
                                                  const float* __restrict__ att1,
                                                  const float* __restrict__ b1,
                                                  const float* __restrict__ W2l,
                                                  const float* __restrict__ W2r,
                                                  float* __restrict__ sl,
                                                  float* __restrict__ sr){
  const int t = threadIdx.x, lane = t & 63, w = t >> 6;
  const int n = blockIdx.x * 4 + w;
  const int f0 = lane * 4;

  // per-wave invariants in registers
  float xrv[4], w0[4], w1[4], w2[4], av[4];
  {
    ushortx4 xw = *(const ushortx4*)(xr + (size_t)n * FDIM + f0);
    float4 a = *(const float4*)(W1e + f0);
    float4 b = *(const float4*)(W1e + FDIM + f0);
    float4 c = *(const float4*)(W1e + 2*FDIM + f0);
    float4 d = *(const float4*)(att1 + f0);
    xrv[0]=bits2f(xw[0]); xrv[1]=bits2f(xw[1]); xrv[2]=bits2f(xw[2]); xrv[3]=bits2f(xw[3]);
    w0[0]=a.x; w0[1]=a.y; w0[2]=a.z; w0[3]=a.w;
    w1[0]=b.x; w1[1]=b.y; w1[2]=b.z; w1[3]=b.w;
    w2[0]=c.x; w2[1]=c.y; w2[2]=c.z; w2[3]=c.w;
    av[0]=d.x; av[1]=d.y; av[2]=d.z; av[3]=d.w;
  }
  const int beg = offsets[n], end = offsets[n + 1];
  const int last = end - 1;

  float m = -1e30f, den = 0.f;
  float acc0 = 0.f, acc1 = 0.f, acc2 = 0.f, acc3 = 0.f;

  // 2-deep pipeline prologue
  float4 rc  = rec[beg];
  float4 rcn = rec[min(beg + 1, last)];
  int src0 = __builtin_amdgcn_readfirstlane(__float_as_int(rc.x));
  ushortx4 raw = *(const ushortx4*)(xl + (size_t)src0 * FDIM + f0);

  for (int j = beg; j < end; j++){
    const float e0 = rc.y, e1 = rc.z, e2 = rc.w;
    // issue next gather (record already resident)
    int srcn = __builtin_amdgcn_readfirstlane(__float_as_int(rcn.x));
    ushortx4 rawn = *(const ushortx4*)(xl + (size_t)srcn * FDIM + f0);
    rc = rcn;
    // issue record load 2 ahead
    rcn = rec[min(j + 2, last)];

    // elementwise + per-head logit partial (4 features)
    float xv0 = bits2f(raw[0]), xv1 = bits2f(raw[1]);
    float xv2 = bits2f(raw[2]), xv3 = bits2f(raw[3]);
    float v0 = xv0 + xrv[0] + e0*w0[0] + e1*w1[0] + e2*w2[0];
    float v1 = xv1 + xrv[1] + e0*w0[1] + e1*w1[1] + e2*w2[1];
    float v2 = xv2 + xrv[2] + e0*w0[2] + e1*w1[2] + e2*w2[2];
    float v3 = xv3 + xrv[3] + e0*w0[3] + e1*w1[3] + e2*w2[3];
    v0 = fmaxf(v0, NEG_SLOPE * v0);
    v1 = fmaxf(v1, NEG_SLOPE * v1);
    v2 = fmaxf(v2, NEG_SLOPE * v2);
    v3 = fmaxf(v3, NEG_SLOPE * v3);
    float pp = v0*av[0] + v1*av[1] + v2*av[2] + v3*av[3];
    // 16-lane (per-head) reduce
    pp += __shfl_xor(pp, 1, 64);
    pp += __shfl_xor(pp, 2, 64);
    pp += __shfl_xor(pp, 4, 64);
    pp += __shfl_xor(pp, 8, 64);

    // deferred-max online softmax (rescale fires ~ln(deg) times per node)
    if (pp > m + RESCALE_THR){
      float corr = __expf(m - pp);
      den *= corr;
      acc0 *= corr; acc1 *= corr; acc2 *= corr; acc3 *= corr;
      m = pp;
    }
    float al = __expf(pp - m);
    den += al;
    acc0 += al * xv0; acc1 += al * xv1; acc2 += al * xv2; acc3 += al * xv3;

    raw = rawn;
  }

  // epilogue: h = acc/den + b1, ELU, project onto W2l/W2r
  float invd = 1.0f / den;
  float4 bb = *(const float4*)(b1 + f0);
  float h0 = acc0 * invd + bb.x;
  float h1 = acc1 * invd + bb.y;
  float h2 = acc2 * invd + bb.z;
  float h3 = acc3 * invd + bb.w;
  h0 = (h0 > 0.f) ? h0 : (__expf(h0) - 1.f);
  h1 = (h1 > 0.f) ? h1 : (__expf(h1) - 1.f);
  h2 = (h2 > 0.f) ? h2 : (__expf(h2) - 1.f);
  h3 = (h3 > 0.f) ? h3 : (__expf(h3) - 1.f);
  float4 wl = *(const float4*)(W2l + f0);
  float4 wr = *(const float4*)(W2r + f0);
  float pa = h0*wl.x + h1*wl.y + h2*wl.z + h3*wl.w;
  float pb = h0*wr.x + h1*wr.y + h2*wr.z + h3*wr.w;
  pa = wave_sum(pa);
  pb = wave_sum(pb);
  if (lane == 0){ sl[n] = pa; sr[n] = pb; }
}

// ---------- layer-2 FUSED: edge logits + online softmax -> scores ----------
__global__ __launch_bounds__(256) void k_attn2(const int* __restrict__ offsets,
                                               const float4* __restrict__ rec,
                                               const float* __restrict__ W2e,
                                               const float* __restrict__ att2,
                                               const float* __restrict__ b2p,
                                               const float* __restrict__ sl,
                                               const float* __restrict__ sr,
                                               float* __restrict__ scores,
                                               float* __restrict__ out){
  int t = threadIdx.x, lane = t & 63;
  int n = blockIdx.x * 4 + (t >> 6);
  if (n >= N_NODESC) return;
  const float attv = att2[0];
  const float w2e0 = W2e[0], w2e1 = W2e[1], w2e2 = W2e[2];
  const float srn = sr[n];
  int beg = offsets[n], end = offsets[n + 1];
  float m = -1e30f, den = 0.f, num = 0.f;
  for (int j = beg + lane; j < end; j += 64){
    float4 rc = rec[j];
    float slv = sl[__float_as_int(rc.x)];
    float v = slv + srn + rc.y*w2e0 + rc.z*w2e1 + rc.w*w2e2;
    v = (v > 0.f) ? v : NEG_SLOPE * v;
    float lg = v * attv;
    float mn = fmaxf(m, lg);
    float corr = __expf(m - mn);
    float pe   = __expf(lg - mn);
    den = den * corr + pe;
    num = num * corr + pe * slv;
    m = mn;
  }
  float mg = wave_max(m);
  float scale = __expf(m - mg);
  float deng = wave_sum(den * scale);
  float numg = wave_sum(num * scale);
  if (lane == 0){
    float s = numg / deng + b2p[0];
    scores[n] = s;
    out[N_NODESC + n] = s;
  }
}

// ---------- global softmax over scores ----------
__device__ __forceinline__ unsigned fkey(float f){
  unsigned u = __float_as_uint(f);
  return u ^ ((u >> 31) ? 0xFFFFFFFFu : 0x80000000u);
}
__device__ __forceinline__ float funkey(unsigned k){
  unsigned u = (k >> 31) ? (k ^ 0x80000000u) : ~k;
  return __uint_as_float(u);
}

__global__ __launch_bounds__(256) void k_smax_max(const float* __restrict__ scores,
                                                  unsigned* __restrict__ redmax){
  float m = -1e30f;
  for (int i = blockIdx.x * blockDim.x + threadIdx.x; i < N_NODESC;
       i += gridDim.x * blockDim.x)
    m = fmaxf(m, scores[i]);
  m = wave_max(m);
  __shared__ float ws_[4];
  int lane = threadIdx.x & 63, w = threadIdx.x >> 6;
  if (lane == 0) ws_[w] = m;
  __syncthreads();
  if (threadIdx.x == 0){
    for (int i = 1; i < 4; i++) m = fmaxf(m, ws_[i]);
    atomicMax(redmax, fkey(m));
  }
}

__global__ __launch_bounds__(256) void k_smax_sum(const float* __restrict__ scores,
                                                  const unsigned* __restrict__ redmax,
                                                  float* __restrict__ redsum){
  float mx = funkey(*redmax);
  float s = 0.f;
  for (int i = blockIdx.x * blockDim.x + threadIdx.x; i < N_NODESC;
       i += gridDim.x * blockDim.x)
    s += __expf(scores[i] - mx);
  s = wave_sum(s);
  __shared__ float ws_[4];
  int lane = threadIdx.x & 63, w = threadIdx.x >> 6;
  if (lane == 0) ws_[w] = s;
  __syncthreads();
  if (threadIdx.x == 0){
    float t = 0.f;
    for (int i = 0; i < 4; i++) t += ws_[i];
    atomicAdd(redsum, t);
  }
}

__global__ __launch_bounds__(256) void k_smax_write(const float* __restrict__ scores,
                                                    const unsigned* __restrict__ redmax,
                                                    const float* __restrict__ redsum,
                                                    float* __restrict__ out){
  int i = blockIdx.x * blockDim.x + threadIdx.x;
  if (i >= N_NODESC) return;
  float mx = funkey(*redmax);
  float inv = 1.0f / (*redsum);
  out[i] = __expf(scores[i] - mx) * inv;
}

extern "C" void kernel_launch(void* const* d_in, const int* in_sizes, int n_in,
                              void* d_out, int out_size, void* d_ws, size_t ws_size,
                              hipStream_t stream) {
  const float* x    = (const float*)d_in[0];
  const float* ea   = (const float*)d_in[1];
  const float* W1l  = (const float*)d_in[2];
  const float* W1r  = (const float*)d_in[3];
  const float* W1e  = (const float*)d_in[4];
  const float* att1 = (const float*)d_in[5];
  const float* b1   = (const float*)d_in[6];
  const float* W2l  = (const float*)d_in[7];
  const float* W2r  = (const float*)d_in[8];
  const float* W2e  = (const float*)d_in[9];
  const float* att2 = (const float*)d_in[10];
  const float* b2   = (const float*)d_in[11];
  const int*   ei   = (const int*)d_in[12];
  float* out = (float*)d_out;

  char* w = (char*)d_ws;
  size_t off = 0;
  auto alloc = [&](size_t bytes) -> char* {
    char* p = w + off;
    off = (off + bytes + 255) & ~(size_t)255;
    return p;
  };
  // ---- zero zone (memset every call) ----
  float*    meanacc = (float*)alloc(16);
  unsigned* redmax  = (unsigned*)alloc(8);
  float*    redsum  = (float*)((char*)redmax + 4);
  int*      deg     = (int*)alloc((size_t)N_NODESC * 4);
  size_t zero_bytes = off;
  // ---- rest ----
  int*   offsets = (int*)alloc((size_t)(N_NODESC + 1) * 4);
  int*   cursor  = (int*)alloc((size_t)N_NODESC * 4);
  int*   pre     = (int*)alloc((size_t)N_NODESC * 4);
  int*   bsum    = (int*)alloc((size_t)SCAN_NB * 4);
  int*   boff    = (int*)alloc((size_t)SCAN_NB * 4);
  float4* rec    = (float4*)alloc((size_t)E_TOTC * 16);
  float* sl      = (float*)alloc((size_t)N_NODESC * 4);
  float* sr      = (float*)alloc((size_t)N_NODESC * 4);
  float* scores  = (float*)alloc((size_t)N_NODESC * 4);
  unsigned short* xb    = (unsigned short*)alloc((size_t)MPAD * IN_DIMC * 2);
  unsigned short* Bfrag = (unsigned short*)alloc((size_t)2 * 128 * 256 * 2);
  unsigned short* xl    = (unsigned short*)alloc((size_t)MPAD * FDIM * 2);
  unsigned short* xr    = (unsigned short*)alloc((size_t)MPAD * FDIM * 2);
  (void)ws_size; (void)in_sizes; (void)n_in; (void)out_size;

  hipMemsetAsync(d_ws, 0, zero_bytes, stream);

  k_mean  <<<400, 256, 0, stream>>>(ea, meanacc);
  k_cvtx  <<<(int)(((size_t)MPAD * IN_DIMC / 4 + 255) / 256), 256, 0, stream>>>(x, xb);
  k_cvtw  <<<256, 256, 0, stream>>>(W1l, W1r, Bfrag);
  k_count <<<(E_TOTC + 255) / 256, 256, 0, stream>>>(ei, deg);
  k_scan_pa<<<SCAN_NB, 256, 0, stream>>>(deg, pre, bsum);
  k_scan_pb<<<1, 64, 0, stream>>>(bsum, boff, offsets);
  k_scan_pc<<<SCAN_NB, 256, 0, stream>>>(pre, boff, offsets, cursor);
  k_scatter<<<(E_TOTC + 255) / 256, 256, 0, stream>>>(ei, ea, meanacc, cursor, rec);
  {
    dim3 g(MPAD / 32, 2);
    k_gemm_mfma<<<g, 256, 0, stream>>>(xb, Bfrag, xl, xr);
  }
  k_attn1 <<<N_NODESC / 4, 256, 0, stream>>>(offsets, rec, xl, xr,
                                             W1e, att1, b1, W2l, W2r, sl, sr);
  k_attn2 <<<(N_NODESC + 3) / 4, 256, 0, stream>>>(offsets, rec, W2e, att2, b2,
                                                   sl, sr, scores, out);
  k_smax_max <<<256, 256, 0, stream>>>(scores, redmax);
  k_smax_sum <<<256, 256, 0, stream>>>(scores, redmax, redsum);
  k_smax_write<<<(N_NODESC + 255) / 256, 256, 0, stream>>>(scores, redmax, redsum, out);
}